// Round 1
// baseline (478.464 us; speedup 1.0000x reference)
//
#include <hip/hip_runtime.h>
#include <math.h>

// ---------------------------------------------------------------------------
// FusionMoE: concat(vis,lang,state) @ Wf -> LN -> GELU -> gate top-2 ->
// dense 4-expert FFN -> residual LN -> weighted combine + lb_loss.
// B=16384, D_IN=1600, D=256, E=4, K=2.
//
// Precision plan: fusion GEMM in split-bf16 (hi/lo, 3 MFMA products) so the
// gate logits are fp32-faithful (top-k flips would blow the 2% threshold).
// Expert GEMMs in plain bf16 (threshold 0.1575 absmax, errors ~5e-3).
// ---------------------------------------------------------------------------

typedef unsigned short u16;
typedef unsigned int u32;
typedef __attribute__((ext_vector_type(8))) short bf16x8;
typedef __attribute__((ext_vector_type(4))) float f32x4;

#define NB 16384
#define DIN 1600
#define DM 256

__device__ __forceinline__ float bf2f(u16 u) {
    union { u32 i; float f; } v; v.i = ((u32)u) << 16; return v.f;
}
__device__ __forceinline__ u16 f2bf(float f) {  // round-to-nearest-even
    union { float f; u32 i; } v; v.f = f;
    u32 x = v.i;
    u32 r = (x + 0x7fffu + ((x >> 16) & 1u)) >> 16;
    return (u16)r;
}
__device__ __forceinline__ float gelu_exact(float v) {
    return 0.5f * v * (1.0f + erff(v * 0.70710678118654752f));
}

typedef __attribute__((address_space(1))) void GV;
typedef __attribute__((address_space(3))) void SV;
__device__ __forceinline__ void gld_lds16(const u16* g, u16* l) {
    // async 16B global->LDS; LDS dest must be wave-uniform base + lane*16
    __builtin_amdgcn_global_load_lds((GV*)g, (SV*)l, 16, 0, 0);
}

// ----- BK=64 tile staging (XOR-8 swizzle: chunk c of row r holds k-chunk c^(r&7)) -----
__device__ __forceinline__ void stageA64(const u16* Ag, int lda, u16* As, int tid) {
#pragma unroll
    for (int i = 0; i < 2; ++i) {
        int s = i * 256 + tid;          // 512 slots of 16B (64 rows x 8 chunks)
        int m = s >> 3, c = s & 7;
        int q = c ^ (m & 7);
        gld_lds16(Ag + m * lda + q * 8, As + s * 8);
    }
}
__device__ __forceinline__ void stageB64(const u16* Bg, int ldb, u16* Bs, int tid) {
#pragma unroll
    for (int i = 0; i < 8; ++i) {
        int s = i * 256 + tid;          // 2048 slots (256 rows x 8 chunks)
        int n = s >> 3, c = s & 7;
        int q = c ^ (n & 7);
        gld_lds16(Bg + n * ldb + q * 8, Bs + s * 8);
    }
}
__device__ __forceinline__ void compute64(const u16* As, const u16* Bs, f32x4 acc[4][4],
                                          int w, int l16, int quad) {
#pragma unroll
    for (int ks = 0; ks < 2; ++ks) {
        bf16x8 a[4];
#pragma unroll
        for (int mt = 0; mt < 4; ++mt) {
            int m = mt * 16 + l16;
            int q = ks * 4 + quad;
            a[mt] = *(const bf16x8*)(As + m * 64 + ((q ^ (m & 7)) << 3));
        }
#pragma unroll
        for (int nt = 0; nt < 4; ++nt) {
            int n = w * 64 + nt * 16 + l16;
            int q = ks * 4 + quad;
            bf16x8 b = *(const bf16x8*)(Bs + n * 64 + ((q ^ (n & 7)) << 3));
#pragma unroll
            for (int mt = 0; mt < 4; ++mt)
                acc[mt][nt] = __builtin_amdgcn_mfma_f32_16x16x32_bf16(a[mt], b, acc[mt][nt], 0, 0, 0);
        }
    }
}
__device__ __forceinline__ void compute64_dual(const u16* AsH, const u16* AsL, const u16* Bs,
                                               f32x4 acc[4][4], int w, int l16, int quad) {
#pragma unroll
    for (int ks = 0; ks < 2; ++ks) {
        bf16x8 ah[4], al[4];
#pragma unroll
        for (int mt = 0; mt < 4; ++mt) {
            int m = mt * 16 + l16;
            int q = ks * 4 + quad;
            int off = m * 64 + ((q ^ (m & 7)) << 3);
            ah[mt] = *(const bf16x8*)(AsH + off);
            al[mt] = *(const bf16x8*)(AsL + off);
        }
#pragma unroll
        for (int nt = 0; nt < 4; ++nt) {
            int n = w * 64 + nt * 16 + l16;
            int q = ks * 4 + quad;
            bf16x8 b = *(const bf16x8*)(Bs + n * 64 + ((q ^ (n & 7)) << 3));
#pragma unroll
            for (int mt = 0; mt < 4; ++mt) {
                acc[mt][nt] = __builtin_amdgcn_mfma_f32_16x16x32_bf16(ah[mt], b, acc[mt][nt], 0, 0, 0);
                acc[mt][nt] = __builtin_amdgcn_mfma_f32_16x16x32_bf16(al[mt], b, acc[mt][nt], 0, 0, 0);
            }
        }
    }
}

// ----- BK=32 variants (combine kernel; keeps total LDS under 64KB) -----
__device__ __forceinline__ void stageA32(const u16* Ag, int lda, u16* As, int tid) {
    int s = tid;                        // 256 slots (64 rows x 4 chunks)
    int m = s >> 2, c = s & 3;
    int q = c ^ (m & 3);
    gld_lds16(Ag + m * lda + q * 8, As + s * 8);
}
__device__ __forceinline__ void stageB32(const u16* Bg, int ldb, u16* Bs, int tid) {
#pragma unroll
    for (int i = 0; i < 4; ++i) {
        int s = i * 256 + tid;          // 1024 slots (256 rows x 4 chunks)
        int n = s >> 2, c = s & 3;
        int q = c ^ (n & 3);
        gld_lds16(Bg + n * ldb + q * 8, Bs + s * 8);
    }
}
__device__ __forceinline__ void compute32(const u16* As, const u16* Bs, f32x4 acc[4][4],
                                          int w, int l16, int quad) {
    bf16x8 a[4];
#pragma unroll
    for (int mt = 0; mt < 4; ++mt) {
        int m = mt * 16 + l16;
        a[mt] = *(const bf16x8*)(As + m * 32 + ((quad ^ (m & 3)) << 3));
    }
#pragma unroll
    for (int nt = 0; nt < 4; ++nt) {
        int n = w * 64 + nt * 16 + l16;
        bf16x8 b = *(const bf16x8*)(Bs + n * 32 + ((quad ^ (n & 3)) << 3));
#pragma unroll
        for (int mt = 0; mt < 4; ++mt)
            acc[mt][nt] = __builtin_amdgcn_mfma_f32_16x16x32_bf16(a[mt], b, acc[mt][nt], 0, 0, 0);
    }
}

// ---------------------------------------------------------------------------
// K0: prep — concat+split(hi/lo) A, transpose/convert weights, zero lb acc
// ---------------------------------------------------------------------------
#define SEG_A   6553600   // 16384*400 float4-groups
#define SEG_WF  409600
#define SEG_W1  524288
#define SEG_W2  524288
#define SEG_W3  262144
#define PREP_ITEMS (SEG_A + SEG_WF + SEG_W1 + SEG_W2 + SEG_W3 + 8)

__global__ __launch_bounds__(256) void prep_kernel(
    const float* __restrict__ vis, const float* __restrict__ lang, const float* __restrict__ state,
    const float* __restrict__ Wf, const float* __restrict__ W1, const float* __restrict__ W2,
    const float* __restrict__ W3,
    u16* __restrict__ ahi, u16* __restrict__ alo,
    u16* __restrict__ wfth, u16* __restrict__ wftl,
    u16* __restrict__ w1t, u16* __restrict__ w2t, u16* __restrict__ w3t,
    float* __restrict__ lbacc) {
    int idx = blockIdx.x * 256 + threadIdx.x;
    if (idx < SEG_A) {
        int row = idx / 400, j4 = idx % 400;
        const float* src;
        if (j4 < 192)      src = vis + (size_t)row * 768 + j4 * 4;
        else if (j4 < 384) src = lang + (size_t)row * 768 + (j4 - 192) * 4;
        else               src = state + (size_t)row * 64 + (j4 - 384) * 4;
        float4 v = *(const float4*)src;
        u16 h0 = f2bf(v.x), h1 = f2bf(v.y), h2 = f2bf(v.z), h3 = f2bf(v.w);
        u16 l0 = f2bf(v.x - bf2f(h0)), l1 = f2bf(v.y - bf2f(h1));
        u16 l2 = f2bf(v.z - bf2f(h2)), l3 = f2bf(v.w - bf2f(h3));
        size_t o = (size_t)row * 1600 + j4 * 4;
        uint2 hp, lp;
        hp.x = (u32)h0 | ((u32)h1 << 16); hp.y = (u32)h2 | ((u32)h3 << 16);
        lp.x = (u32)l0 | ((u32)l1 << 16); lp.y = (u32)l2 | ((u32)l3 << 16);
        *(uint2*)(ahi + o) = hp;
        *(uint2*)(alo + o) = lp;
        return;
    }
    idx -= SEG_A;
    if (idx < SEG_WF) {  // WfT[n][k] = Wf[k][n], hi+lo
        int n = idx / 1600, k = idx % 1600;
        float v = Wf[(size_t)k * 256 + n];
        u16 h = f2bf(v);
        wfth[idx] = h;
        wftl[idx] = f2bf(v - bf2f(h));
        return;
    }
    idx -= SEG_WF;
    if (idx < SEG_W1) {  // W1T[e][n<512][k<256] = W1[e][k][n]
        int e = idx >> 17, r = idx & 131071;
        int n = r >> 8, k = r & 255;
        w1t[idx] = f2bf(W1[(size_t)e * 131072 + (size_t)k * 512 + n]);
        return;
    }
    idx -= SEG_W1;
    if (idx < SEG_W2) {  // W2T[e][n<256][k<512] = W2[e][k][n]
        int e = idx >> 17, r = idx & 131071;
        int n = r >> 9, k = r & 511;
        w2t[idx] = f2bf(W2[(size_t)e * 131072 + (size_t)k * 256 + n]);
        return;
    }
    idx -= SEG_W2;
    if (idx < SEG_W3) {  // W3T[e][n<256][k<256] = W3[e][k][n]
        int e = idx >> 16, r = idx & 65535;
        int n = r >> 8, k = r & 255;
        w3t[idx] = f2bf(W3[(size_t)e * 65536 + (size_t)k * 256 + n]);
        return;
    }
    idx -= SEG_W3;
    if (idx < 8) lbacc[idx] = 0.0f;
}

// ---------------------------------------------------------------------------
// K1: fusion GEMM (split-bf16, 3 products) + bias + LN + GELU -> x_f32, x_bf16
// tile: 64 rows x 256 cols (full row => LN in-block). 4 waves of 64x64.
// ---------------------------------------------------------------------------
__global__ __launch_bounds__(256) void fusion_kernel(
    const u16* __restrict__ AHI, const u16* __restrict__ ALO,
    const u16* __restrict__ BTH, const u16* __restrict__ BTL,
    const float* __restrict__ bfv_, const float* __restrict__ gf, const float* __restrict__ bfln,
    float* __restrict__ xf, u16* __restrict__ xbf) {
    __shared__ __align__(16) u16 AsH[4096];
    __shared__ __align__(16) u16 AsL[4096];
    __shared__ __align__(16) u16 BsH[16384];
    int tid = threadIdx.x;
    int w = tid >> 6, lane = tid & 63, quad = lane >> 4, l16 = lane & 15;
    int m0 = blockIdx.x * 64;
    f32x4 acc[4][4] = {};
    const u16* AgH = AHI + (size_t)m0 * 1600;
    const u16* AgL = ALO + (size_t)m0 * 1600;
    // phase 1: hi*hi + lo*hi
    for (int kit = 0; kit < 25; ++kit) {
        stageA64(AgH + kit * 64, 1600, AsH, tid);
        stageA64(AgL + kit * 64, 1600, AsL, tid);
        stageB64(BTH + kit * 64, 1600, BsH, tid);
        __syncthreads();
        compute64_dual(AsH, AsL, BsH, acc, w, l16, quad);
        __syncthreads();
    }
    // phase 2: hi*lo
    for (int kit = 0; kit < 25; ++kit) {
        stageA64(AgH + kit * 64, 1600, AsH, tid);
        stageB64(BTL + kit * 64, 1600, BsH, tid);
        __syncthreads();
        compute64(AsH, BsH, acc, w, l16, quad);
        __syncthreads();
    }
    // epilogue: + bf, LayerNorm over 256, *gf+bfln, GELU
    float bfv[4], gfv[4], blv[4];
#pragma unroll
    for (int nt = 0; nt < 4; ++nt) {
        int col = w * 64 + nt * 16 + l16;
        bfv[nt] = bfv_[col]; gfv[nt] = gf[col]; blv[nt] = bfln[col];
    }
#pragma unroll
    for (int mt = 0; mt < 4; ++mt)
#pragma unroll
        for (int nt = 0; nt < 4; ++nt)
#pragma unroll
            for (int r = 0; r < 4; ++r) acc[mt][nt][r] += bfv[nt];

    float2* red = (float2*)AsL;                       // alias (staging done)
    float* muv = (float*)((char*)AsL + 2048);
    float* rsv = (float*)((char*)AsL + 2048 + 256);
#pragma unroll
    for (int mt = 0; mt < 4; ++mt)
#pragma unroll
        for (int r = 0; r < 4; ++r) {
            float ss = 0.f, qq = 0.f;
#pragma unroll
            for (int nt = 0; nt < 4; ++nt) { float v = acc[mt][nt][r]; ss += v; qq += v * v; }
#pragma unroll
            for (int d = 1; d < 16; d <<= 1) { ss += __shfl_xor(ss, d); qq += __shfl_xor(qq, d); }
            if (l16 == 0) red[w * 64 + mt * 16 + quad * 4 + r] = make_float2(ss, qq);
        }
    __syncthreads();
    if (tid < 64) {
        float ss = 0.f, qq = 0.f;
#pragma unroll
        for (int ww = 0; ww < 4; ++ww) { float2 t = red[ww * 64 + tid]; ss += t.x; qq += t.y; }
        float mu = ss * (1.f / 256.f);
        float var = qq * (1.f / 256.f) - mu * mu;
        muv[tid] = mu;
        rsv[tid] = 1.f / sqrtf(var + 1e-5f);
    }
    __syncthreads();
#pragma unroll
    for (int mt = 0; mt < 4; ++mt)
#pragma unroll
        for (int r = 0; r < 4; ++r) {
            int rl = mt * 16 + quad * 4 + r;
            float mu = muv[rl], rs = rsv[rl];
#pragma unroll
            for (int nt = 0; nt < 4; ++nt) {
                int col = w * 64 + nt * 16 + l16;
                float v = (acc[mt][nt][r] - mu) * rs;
                v = v * gfv[nt] + blv[nt];
                float g = gelu_exact(v);
                size_t gi = (size_t)(m0 + rl) * 256 + col;
                xf[gi] = g;
                xbf[gi] = f2bf(g);
            }
        }
}

// ---------------------------------------------------------------------------
// K2: gate — fp32 logits, softmax, top-2 (jax tie-break: lower index), lb atomics
// one wave per row, 16 waves/block
// ---------------------------------------------------------------------------
__global__ __launch_bounds__(1024) void gate_kernel(
    const float* __restrict__ xf, const float* __restrict__ Wg,
    float* __restrict__ wr, float* __restrict__ lbacc) {
    __shared__ float sacc[8];
    int tid = threadIdx.x;
    if (tid < 8) sacc[tid] = 0.f;
    __syncthreads();
    int wv = tid >> 6, lane = tid & 63;
    int row = blockIdx.x * 16 + wv;
    float4 xv = *(const float4*)(xf + (size_t)row * 256 + lane * 4);
    float p[4] = {0.f, 0.f, 0.f, 0.f};
#pragma unroll
    for (int i = 0; i < 4; ++i) {
        float xx = (i == 0) ? xv.x : (i == 1) ? xv.y : (i == 2) ? xv.z : xv.w;
        float4 wg = *(const float4*)(Wg + (size_t)(lane * 4 + i) * 4);
        p[0] += xx * wg.x; p[1] += xx * wg.y; p[2] += xx * wg.z; p[3] += xx * wg.w;
    }
#pragma unroll
    for (int d = 1; d < 64; d <<= 1) {
#pragma unroll
        for (int e = 0; e < 4; ++e) p[e] += __shfl_xor(p[e], d);
    }
    if (lane == 0) {
        float mx = fmaxf(fmaxf(p[0], p[1]), fmaxf(p[2], p[3]));
        float ex[4]; float Z = 0.f;
#pragma unroll
        for (int e = 0; e < 4; ++e) { ex[e] = expf(p[e] - mx); Z += ex[e]; }
        int i0 = 0; float v0 = p[0];
#pragma unroll
        for (int e = 1; e < 4; ++e) if (p[e] > v0) { v0 = p[e]; i0 = e; }
        int i1 = -1; float v1 = -1e30f;
#pragma unroll
        for (int e = 0; e < 4; ++e) if (e != i0 && p[e] > v1) { v1 = p[e]; i1 = e; }
        float t = expf(v1 - v0);
        float wA = 1.f / (1.f + t);
        float wB = t / (1.f + t);
        float w4[4] = {0.f, 0.f, 0.f, 0.f};
        w4[i0] = wA; w4[i1] = wB;
#pragma unroll
        for (int e = 0; e < 4; ++e) wr[(size_t)row * 4 + e] = w4[e];
#pragma unroll
        for (int e = 0; e < 4; ++e) atomicAdd(&sacc[e], ex[e] / Z);
        atomicAdd(&sacc[4 + i0], 1.f);
        atomicAdd(&sacc[4 + i1], 1.f);
    }
    __syncthreads();
    if (tid < 8) atomicAdd(lbacc + tid, sacc[tid]);
}

// ---------------------------------------------------------------------------
// K3/K4: expert GEMM + bias + GELU -> bf16 (layers 1 and 2)
// ---------------------------------------------------------------------------
__global__ __launch_bounds__(256) void gemm_gelu_kernel(
    const u16* __restrict__ A, int lda, const u16* __restrict__ BT,
    const float* __restrict__ bias, u16* __restrict__ outp, int ldo) {
    __shared__ __align__(16) u16 As[4096];
    __shared__ __align__(16) u16 Bs[16384];
    int tid = threadIdx.x;
    int w = tid >> 6, lane = tid & 63, quad = lane >> 4, l16 = lane & 15;
    int m0 = blockIdx.x * 64;
    int col0 = blockIdx.y * 256;
    f32x4 acc[4][4] = {};
    const u16* Ag = A + (size_t)m0 * lda;
    const u16* Bg = BT + (size_t)col0 * lda;
    int kiters = lda >> 6;
    for (int kit = 0; kit < kiters; ++kit) {
        stageA64(Ag + kit * 64, lda, As, tid);
        stageB64(Bg + kit * 64, lda, Bs, tid);
        __syncthreads();
        compute64(As, Bs, acc, w, l16, quad);
        __syncthreads();
    }
#pragma unroll
    for (int nt = 0; nt < 4; ++nt) {
        int col = col0 + w * 64 + nt * 16 + l16;
        float bv = bias[col];
#pragma unroll
        for (int mt = 0; mt < 4; ++mt)
#pragma unroll
            for (int r = 0; r < 4; ++r) {
                int row = m0 + mt * 16 + quad * 4 + r;
                float v = acc[mt][nt][r] + bv;
                outp[(size_t)row * ldo + col] = f2bf(gelu_exact(v));
            }
    }
}

// ---------------------------------------------------------------------------
// K5: combine — per 64-row tile, loop e: h2@W3 + b3 + x -> LN -> *eg+eb,
// out += w[row][e] * y. BK=32 so LDS stays under 64KB with x tile resident.
// ---------------------------------------------------------------------------
__global__ __launch_bounds__(256) void combine_kernel(
    const u16* __restrict__ h2, const u16* __restrict__ W3T,
    const float* __restrict__ b3, const float* __restrict__ eg, const float* __restrict__ eb,
    const u16* __restrict__ xbf, const float* __restrict__ wr, float* __restrict__ outp) {
    __shared__ __align__(16) u16 As[2048];
    __shared__ __align__(16) u16 Bs[8192];
    __shared__ __align__(16) u16 xs[16384];
    __shared__ float wl[256];
    int tid = threadIdx.x;
    int w = tid >> 6, lane = tid & 63, quad = lane >> 4, l16 = lane & 15;
    int m0 = blockIdx.x * 64;
#pragma unroll
    for (int i = 0; i < 8; ++i) {
        int s = i * 256 + tid;
        *(uint4*)(xs + s * 8) = *(const uint4*)(xbf + (size_t)m0 * 256 + s * 8);
    }
    wl[tid] = wr[(size_t)m0 * 4 + tid];
    float2* red = (float2*)As;                   // alias (epilogue-only use)
    float* muv = (float*)((char*)As + 2048);
    float* rsv = (float*)((char*)As + 2048 + 256);
    f32x4 oacc[4][4] = {};
    for (int e = 0; e < 4; ++e) {
        __syncthreads();   // covers xs/wl (e=0) and red/mu reads (e>0)
        f32x4 acc[4][4] = {};
        const u16* Ag = h2 + ((size_t)e * 16384 + m0) * 256;
        const u16* Bg = W3T + (size_t)e * 65536;
        for (int kit = 0; kit < 8; ++kit) {
            stageA32(Ag + kit * 32, 256, As, tid);
            stageB32(Bg + kit * 32, 256, Bs, tid);
            __syncthreads();
            compute32(As, Bs, acc, w, l16, quad);
            __syncthreads();
        }
        float b3v[4], egv[4], ebv[4];
#pragma unroll
        for (int nt = 0; nt < 4; ++nt) {
            int col = w * 64 + nt * 16 + l16;
            b3v[nt] = b3[e * 256 + col]; egv[nt] = eg[e * 256 + col]; ebv[nt] = eb[e * 256 + col];
        }
#pragma unroll
        for (int mt = 0; mt < 4; ++mt)
#pragma unroll
            for (int r = 0; r < 4; ++r) {
                int rl = mt * 16 + quad * 4 + r;
                float ss = 0.f, qq = 0.f;
#pragma unroll
                for (int nt = 0; nt < 4; ++nt) {
                    int col = w * 64 + nt * 16 + l16;
                    float v = acc[mt][nt][r] + b3v[nt] + bf2f(xs[rl * 256 + col]);
                    acc[mt][nt][r] = v;
                    ss += v; qq += v * v;
                }
#pragma unroll
                for (int d = 1; d < 16; d <<= 1) { ss += __shfl_xor(ss, d); qq += __shfl_xor(qq, d); }
                if (l16 == 0) red[w * 64 + rl] = make_float2(ss, qq);
            }
        __syncthreads();
        if (tid < 64) {
            float ss = 0.f, qq = 0.f;
#pragma unroll
            for (int ww = 0; ww < 4; ++ww) { float2 t = red[ww * 64 + tid]; ss += t.x; qq += t.y; }
            float mu = ss * (1.f / 256.f);
            float var = qq * (1.f / 256.f) - mu * mu;
            muv[tid] = mu;
            rsv[tid] = 1.f / sqrtf(var + 1e-5f);
        }
        __syncthreads();
#pragma unroll
        for (int mt = 0; mt < 4; ++mt)
#pragma unroll
            for (int r = 0; r < 4; ++r) {
                int rl = mt * 16 + quad * 4 + r;
                float mu = muv[rl], rs = rsv[rl], we = wl[rl * 4 + e];
#pragma unroll
                for (int nt = 0; nt < 4; ++nt) {
                    float y = (acc[mt][nt][r] - mu) * rs * egv[nt] + ebv[nt];
                    oacc[mt][nt][r] += we * y;
                }
            }
    }
#pragma unroll
    for (int mt = 0; mt < 4; ++mt)
#pragma unroll
        for (int r = 0; r < 4; ++r) {
            int rl = mt * 16 + quad * 4 + r;
#pragma unroll
            for (int nt = 0; nt < 4; ++nt) {
                int col = w * 64 + nt * 16 + l16;
                outp[(size_t)(m0 + rl) * 256 + col] = oacc[mt][nt][r];
            }
        }
}

__global__ void lbfinal_kernel(const float* __restrict__ lbacc, float* __restrict__ outp) {
    if (threadIdx.x == 0 && blockIdx.x == 0) {
        float lb = 0.f;
#pragma unroll
        for (int e = 0; e < 4; ++e)
            lb += (lbacc[4 + e] / 32768.f) * (lbacc[e] / 16384.f);
        outp[4194304] = 4.f * lb;
    }
}

// ---------------------------------------------------------------------------
extern "C" void kernel_launch(void* const* d_in, const int* in_sizes, int n_in,
                              void* d_out, int out_size, void* d_ws, size_t ws_size,
                              hipStream_t stream) {
    const float* vis   = (const float*)d_in[0];
    const float* lang  = (const float*)d_in[1];
    const float* state = (const float*)d_in[2];
    const float* Wf    = (const float*)d_in[3];
    const float* bf_   = (const float*)d_in[4];
    const float* gf    = (const float*)d_in[5];
    const float* bfln  = (const float*)d_in[6];
    const float* Wg    = (const float*)d_in[7];
    const float* W1    = (const float*)d_in[8];
    const float* b1    = (const float*)d_in[9];
    const float* W2    = (const float*)d_in[10];
    const float* b2    = (const float*)d_in[11];
    const float* W3    = (const float*)d_in[12];
    const float* b3    = (const float*)d_in[13];
    const float* eg    = (const float*)d_in[14];
    const float* eb    = (const float*)d_in[15];
    float* outp = (float*)d_out;

    char* ws = (char*)d_ws;
    size_t off = 0;
    float* lbacc = (float*)(ws + off); off += 256;
    u16* AHI  = (u16*)(ws + off); off += 52428800UL;   // [B][1600] bf16 hi
    u16* ALO  = (u16*)(ws + off); off += 52428800UL;   // [B][1600] bf16 lo
    u16* WFTH = (u16*)(ws + off); off += 819200UL;     // WfT hi [256][1600]
    u16* WFTL = (u16*)(ws + off); off += 819200UL;     // WfT lo
    u16* W1T  = (u16*)(ws + off); off += 1048576UL;    // [E][512][256]
    u16* W2T  = (u16*)(ws + off); off += 1048576UL;    // [E][256][512]
    u16* W3T  = (u16*)(ws + off); off += 524288UL;     // [E][256][256]
    float* XF = (float*)(ws + off); off += 16777216UL; // x fp32 [B][256]
    u16* XBF  = (u16*)(ws + off); off += 8388608UL;    // x bf16
    float* WR = (float*)(ws + off); off += 262144UL;   // gate weights [B][4]
    u16* H1   = (u16*)(ws + off); off += 16777216UL;   // [B][512] (per-e reuse)
    u16* H2   = (u16*)(ws + off); off += 33554432UL;   // [E][B][256]
    if (ws_size < off) return;  // workspace too small — fail loudly via mismatch

    int prep_blocks = (PREP_ITEMS + 255) / 256;
    prep_kernel<<<prep_blocks, 256, 0, stream>>>(vis, lang, state, Wf, W1, W2, W3,
                                                 AHI, ALO, WFTH, WFTL, W1T, W2T, W3T, lbacc);
    fusion_kernel<<<256, 256, 0, stream>>>(AHI, ALO, WFTH, WFTL, bf_, gf, bfln, XF, XBF);
    gate_kernel<<<1024, 1024, 0, stream>>>(XF, Wg, WR, lbacc);
    for (int e = 0; e < 4; ++e) {
        gemm_gelu_kernel<<<dim3(256, 2), 256, 0, stream>>>(XBF, 256, W1T + (size_t)e * 131072,
                                                           b1 + e * 512, H1, 512);
        gemm_gelu_kernel<<<dim3(256, 1), 256, 0, stream>>>(H1, 512, W2T + (size_t)e * 131072,
                                                           b2 + e * 256, H2 + (size_t)e * 4194304, 256);
    }
    combine_kernel<<<256, 256, 0, stream>>>(H2, W3T, b3, eg, eb, XBF, WR, outp);
    lbfinal_kernel<<<1, 64, 0, stream>>>(lbacc, outp);
}

// Round 2
// 322.374 us; speedup vs baseline: 1.4842x; 1.4842x over previous
//
#include <hip/hip_runtime.h>
#include <math.h>

// ---------------------------------------------------------------------------
// FusionMoE R2: plain bf16 MFMA everywhere (flip analysis: expert outputs
// differ by ~0.012, top-k flips cost <0.01 absmax vs 0.1575 threshold).
// fusion reads fp32 A directly (perm-pack), gate fused into fusion epilogue,
// expert layers batched over blockIdx.z, 2-4 blocks/CU everywhere.
// ---------------------------------------------------------------------------

typedef unsigned short u16;
typedef unsigned int u32;
typedef __attribute__((ext_vector_type(8))) short bf16x8;
typedef __attribute__((ext_vector_type(4))) float f32x4;

__device__ __forceinline__ float bf2f(u16 u) {
    union { u32 i; float f; } v; v.i = ((u32)u) << 16; return v.f;
}
__device__ __forceinline__ u16 f2bf(float f) {  // RNE
    union { float f; u32 i; } v; v.f = f;
    u32 x = v.i;
    return (u16)((x + 0x7fffu + ((x >> 16) & 1u)) >> 16);
}
__device__ __forceinline__ float gelu_exact(float v) {
    return 0.5f * v * (1.0f + erff(v * 0.70710678118654752f));
}

typedef __attribute__((address_space(1))) void GV;
typedef __attribute__((address_space(3))) void SV;
__device__ __forceinline__ void gldlds(const void* g, void* l) {
    __builtin_amdgcn_global_load_lds((GV*)g, (SV*)l, 16, 0, 0);
}

// pack two f32 (bit-truncate) into one u32 of two bf16 (f0 low, f1 high)
__device__ __forceinline__ u32 pk2(u32 f0, u32 f1) {
    return __builtin_amdgcn_perm(f1, f0, 0x07060302);
}

// ----- bf16 staging helpers (XOR-8 swizzle), verified in R1 -----
__device__ __forceinline__ void stageA64(const u16* Ag, int lda, u16* As, int tid) {
#pragma unroll
    for (int i = 0; i < 2; ++i) {
        int s = i * 256 + tid;          // 512 slots (64 rows x 8 chunks of 16B)
        int m = s >> 3, c = s & 7;
        gldlds(Ag + m * lda + (c ^ (m & 7)) * 8, As + s * 8);
    }
}
__device__ __forceinline__ void stageA64_R32(const u16* Ag, int lda, u16* As, int tid) {
    int s = tid;                        // 256 slots (32 rows x 8 chunks)
    int m = s >> 3, c = s & 7;
    gldlds(Ag + m * lda + (c ^ (m & 7)) * 8, As + s * 8);
}
__device__ __forceinline__ void stageB64(const u16* Bg, int ldb, u16* Bs, int tid) {
#pragma unroll
    for (int i = 0; i < 8; ++i) {
        int s = i * 256 + tid;          // 2048 slots (256 n-rows x 8 chunks)
        int n = s >> 3, c = s & 7;
        gldlds(Bg + n * ldb + (c ^ (n & 7)) * 8, Bs + s * 8);
    }
}
__device__ __forceinline__ void compute64(const u16* As, const u16* Bs, f32x4 acc[4][4],
                                          int w, int l16, int quad) {
#pragma unroll
    for (int ks = 0; ks < 2; ++ks) {
        bf16x8 a[4];
#pragma unroll
        for (int mt = 0; mt < 4; ++mt) {
            int m = mt * 16 + l16;
            a[mt] = *(const bf16x8*)(As + m * 64 + (((ks * 4 + quad) ^ (m & 7)) << 3));
        }
#pragma unroll
        for (int nt = 0; nt < 4; ++nt) {
            int n = w * 64 + nt * 16 + l16;
            bf16x8 b = *(const bf16x8*)(Bs + n * 64 + (((ks * 4 + quad) ^ (n & 7)) << 3));
#pragma unroll
            for (int mt = 0; mt < 4; ++mt)
                acc[mt][nt] = __builtin_amdgcn_mfma_f32_16x16x32_bf16(a[mt], b, acc[mt][nt], 0, 0, 0);
        }
    }
}
__device__ __forceinline__ void compute64_R32(const u16* As, const u16* Bs, f32x4 acc[2][4],
                                              int w, int l16, int quad) {
#pragma unroll
    for (int ks = 0; ks < 2; ++ks) {
        bf16x8 a[2];
#pragma unroll
        for (int mt = 0; mt < 2; ++mt) {
            int m = mt * 16 + l16;
            a[mt] = *(const bf16x8*)(As + m * 64 + (((ks * 4 + quad) ^ (m & 7)) << 3));
        }
#pragma unroll
        for (int nt = 0; nt < 4; ++nt) {
            int n = w * 64 + nt * 16 + l16;
            bf16x8 b = *(const bf16x8*)(Bs + n * 64 + (((ks * 4 + quad) ^ (n & 7)) << 3));
#pragma unroll
            for (int mt = 0; mt < 2; ++mt)
                acc[mt][nt] = __builtin_amdgcn_mfma_f32_16x16x32_bf16(a[mt], b, acc[mt][nt], 0, 0, 0);
        }
    }
}

// ---------------------------------------------------------------------------
// K0: prep — weight transposes to bf16 + lbacc zero (weights only, ~7 MB)
// ---------------------------------------------------------------------------
#define SEG_WF  409600
#define SEG_W1  524288
#define SEG_W2  524288
#define SEG_W3  262144
#define PREP_ITEMS (SEG_WF + SEG_W1 + SEG_W2 + SEG_W3 + 8)

__global__ __launch_bounds__(256) void prep_kernel(
    const float* __restrict__ Wf, const float* __restrict__ W1, const float* __restrict__ W2,
    const float* __restrict__ W3,
    u16* __restrict__ wft, u16* __restrict__ w1t, u16* __restrict__ w2t, u16* __restrict__ w3t,
    float* __restrict__ lbacc) {
    int idx = blockIdx.x * 256 + threadIdx.x;
    if (idx < SEG_WF) {  // WfT[n<256][k<1600] = Wf[k][n]
        int n = idx / 1600, k = idx % 1600;
        wft[idx] = f2bf(Wf[(size_t)k * 256 + n]);
        return;
    }
    idx -= SEG_WF;
    if (idx < SEG_W1) {  // W1T[e][n<512][k<256] = W1[e][k][n]
        int e = idx >> 17, r = idx & 131071;
        int n = r >> 8, k = r & 255;
        w1t[idx] = f2bf(W1[(size_t)e * 131072 + (size_t)k * 512 + n]);
        return;
    }
    idx -= SEG_W1;
    if (idx < SEG_W2) {  // W2T[e][n<256][k<512] = W2[e][k][n]
        int e = idx >> 17, r = idx & 131071;
        int n = r >> 9, k = r & 511;
        w2t[idx] = f2bf(W2[(size_t)e * 131072 + (size_t)k * 256 + n]);
        return;
    }
    idx -= SEG_W2;
    if (idx < SEG_W3) {  // W3T[e][n<256][k<256] = W3[e][k][n]
        int e = idx >> 16, r = idx & 65535;
        int n = r >> 8, k = r & 255;
        w3t[idx] = f2bf(W3[(size_t)e * 65536 + (size_t)k * 256 + n]);
        return;
    }
    idx -= SEG_W3;
    if (idx < 8) lbacc[idx] = 0.0f;
}

// ---------------------------------------------------------------------------
// K1: fusion — direct fp32 A (concat resolved per kit), bf16 B, 32x256 tile,
// epilogue: bias+LN+GELU -> xbf, fused gate (fp32 logits) -> wr + lb atomics
// ---------------------------------------------------------------------------
__global__ __launch_bounds__(256) void fusion_kernel(
    const float* __restrict__ vis, const float* __restrict__ lang, const float* __restrict__ state,
    const u16* __restrict__ BT, const float* __restrict__ bfv_, const float* __restrict__ gf,
    const float* __restrict__ bfln, const float* __restrict__ Wg,
    u16* __restrict__ xbf, float* __restrict__ wr, float* __restrict__ lbacc) {
    __shared__ __align__(16) u32 Af[2048];   // 8KB: 32 rows x 16 f32-chunks (XOR-16 swizzle)
    __shared__ __align__(16) u16 Bs[16384];  // 32KB: 256 n x 64 k bf16
    int tid = threadIdx.x;
    int w = tid >> 6, lane = tid & 63, quad = lane >> 4, l16 = lane & 15;
    int m0 = blockIdx.x * 32;
    f32x4 acc[2][4] = {};

    for (int kit = 0; kit < 25; ++kit) {
        const float* base; int ld;
        if (kit < 12)      { base = vis   + (size_t)m0 * 768 + kit * 64;        ld = 768; }
        else if (kit < 24) { base = lang  + (size_t)m0 * 768 + (kit - 12) * 64; ld = 768; }
        else               { base = state + (size_t)m0 * 64;                    ld = 64; }
#pragma unroll
        for (int i = 0; i < 2; ++i) {        // A: 512 slots of 16B (4 f32)
            int s = i * 256 + tid;
            int m = s >> 4, c = s & 15;
            gldlds(base + m * ld + (c ^ (m & 15)) * 4, Af + s * 4);
        }
        stageB64(BT + kit * 64, 1600, Bs, tid);
        __syncthreads();
#pragma unroll
        for (int ks = 0; ks < 2; ++ks) {
            bf16x8 a[2];
#pragma unroll
            for (int mt = 0; mt < 2; ++mt) {
                int m = mt * 16 + l16;
                int c0 = ks * 8 + quad * 2;
                const u32* rowp = Af + m * 64;
                uint4 f0 = *(const uint4*)(rowp + (c0 ^ (m & 15)) * 4);
                uint4 f1 = *(const uint4*)(rowp + ((c0 + 1) ^ (m & 15)) * 4);
                union { u32 u[4]; bf16x8 v; } pk;
                pk.u[0] = pk2(f0.x, f0.y); pk.u[1] = pk2(f0.z, f0.w);
                pk.u[2] = pk2(f1.x, f1.y); pk.u[3] = pk2(f1.z, f1.w);
                a[mt] = pk.v;
            }
#pragma unroll
            for (int nt = 0; nt < 4; ++nt) {
                int n = w * 64 + nt * 16 + l16;
                bf16x8 b = *(const bf16x8*)(Bs + n * 64 + (((ks * 4 + quad) ^ (n & 7)) << 3));
#pragma unroll
                for (int mt = 0; mt < 2; ++mt)
                    acc[mt][nt] = __builtin_amdgcn_mfma_f32_16x16x32_bf16(a[mt], b, acc[mt][nt], 0, 0, 0);
            }
        }
        __syncthreads();
    }

    // ---- epilogue: bias, LN, GELU, xbf store, fused gate ----
    float2* red  = (float2*)Af;            // 128 float2 (w*32+rl)
    float*  muv  = (float*)(Af + 256);     // 32
    float*  rsv  = (float*)(Af + 288);     // 32
    float*  gred = (float*)(Af + 512);     // 512: [w][rl][e]
    float*  sacc = (float*)(Af + 1024);    // 8

    float bv[4], gvv[4], blv[4]; float4 wgv[4];
#pragma unroll
    for (int nt = 0; nt < 4; ++nt) {
        int col = w * 64 + nt * 16 + l16;
        bv[nt] = bfv_[col]; gvv[nt] = gf[col]; blv[nt] = bfln[col];
        wgv[nt] = *(const float4*)(Wg + col * 4);
    }
    if (tid < 8) sacc[tid] = 0.f;
#pragma unroll
    for (int mt = 0; mt < 2; ++mt)
#pragma unroll
        for (int r = 0; r < 4; ++r) {
            float ss = 0.f, qq = 0.f;
#pragma unroll
            for (int nt = 0; nt < 4; ++nt) {
                float v = acc[mt][nt][r] + bv[nt];
                acc[mt][nt][r] = v;
                ss += v; qq += v * v;
            }
#pragma unroll
            for (int d = 1; d < 16; d <<= 1) { ss += __shfl_xor(ss, d); qq += __shfl_xor(qq, d); }
            if (l16 == 0) red[w * 32 + mt * 16 + quad * 4 + r] = make_float2(ss, qq);
        }
    __syncthreads();
    if (tid < 32) {
        float ss = 0.f, qq = 0.f;
#pragma unroll
        for (int ww = 0; ww < 4; ++ww) { float2 t = red[ww * 32 + tid]; ss += t.x; qq += t.y; }
        float mu = ss * (1.f / 256.f);
        float var = qq * (1.f / 256.f) - mu * mu;
        muv[tid] = mu;
        rsv[tid] = 1.f / sqrtf(var + 1e-5f);
    }
    __syncthreads();
#pragma unroll
    for (int mt = 0; mt < 2; ++mt)
#pragma unroll
        for (int r = 0; r < 4; ++r) {
            int rl = mt * 16 + quad * 4 + r;
            float mu = muv[rl], rs = rsv[rl];
#pragma unroll
            for (int nt = 0; nt < 4; ++nt) {
                int col = w * 64 + nt * 16 + l16;
                float t = (acc[mt][nt][r] - mu) * rs * gvv[nt] + blv[nt];
                float g = gelu_exact(t);
                acc[mt][nt][r] = g;
                xbf[(size_t)(m0 + rl) * 256 + col] = f2bf(g);
            }
        }
    // gate partials (fp32 x, pre-bf16-truncation)
#pragma unroll
    for (int mt = 0; mt < 2; ++mt)
#pragma unroll
        for (int r = 0; r < 4; ++r) {
            int rl = mt * 16 + quad * 4 + r;
            float p0 = 0.f, p1 = 0.f, p2 = 0.f, p3 = 0.f;
#pragma unroll
            for (int nt = 0; nt < 4; ++nt) {
                float g = acc[mt][nt][r];
                p0 += g * wgv[nt].x; p1 += g * wgv[nt].y;
                p2 += g * wgv[nt].z; p3 += g * wgv[nt].w;
            }
#pragma unroll
            for (int d = 1; d < 16; d <<= 1) {
                p0 += __shfl_xor(p0, d); p1 += __shfl_xor(p1, d);
                p2 += __shfl_xor(p2, d); p3 += __shfl_xor(p3, d);
            }
            if (l16 == 0) {
                float* gp = gred + w * 128 + rl * 4;
                gp[0] = p0; gp[1] = p1; gp[2] = p2; gp[3] = p3;
            }
        }
    __syncthreads();
    if (tid < 32) {
        int row = tid;
        float lg[4];
#pragma unroll
        for (int e = 0; e < 4; ++e)
            lg[e] = gred[row * 4 + e] + gred[128 + row * 4 + e] +
                    gred[256 + row * 4 + e] + gred[384 + row * 4 + e];
        float mx = fmaxf(fmaxf(lg[0], lg[1]), fmaxf(lg[2], lg[3]));
        float ex[4]; float Z = 0.f;
#pragma unroll
        for (int e = 0; e < 4; ++e) { ex[e] = expf(lg[e] - mx); Z += ex[e]; }
        int i0 = 0; float v0 = lg[0];
#pragma unroll
        for (int e = 1; e < 4; ++e) if (lg[e] > v0) { v0 = lg[e]; i0 = e; }
        int i1 = -1; float v1 = -1e30f;
#pragma unroll
        for (int e = 0; e < 4; ++e) if (e != i0 && lg[e] > v1) { v1 = lg[e]; i1 = e; }
        float t = expf(v1 - v0);
        float wA = 1.f / (1.f + t), wB = t / (1.f + t);
        float w4[4] = {0.f, 0.f, 0.f, 0.f};
        w4[i0] = wA; w4[i1] = wB;
#pragma unroll
        for (int e = 0; e < 4; ++e) wr[(size_t)(m0 + row) * 4 + e] = w4[e];
#pragma unroll
        for (int e = 0; e < 4; ++e) atomicAdd(&sacc[e], ex[e] / Z);
        atomicAdd(&sacc[4 + i0], 1.f);
        atomicAdd(&sacc[4 + i1], 1.f);
    }
    __syncthreads();
    if (tid < 8) atomicAdd(lbacc + tid, sacc[tid]);
}

// ---------------------------------------------------------------------------
// K2: expert GEMM + bias + GELU, batched over blockIdx.z = expert
// ---------------------------------------------------------------------------
__global__ __launch_bounds__(256) void expert_gemm_kernel(
    const u16* __restrict__ A, int lda, size_t aE,
    const u16* __restrict__ BT, size_t bE,
    const float* __restrict__ bias, int biasE,
    u16* __restrict__ outp, int ldo, size_t oE) {
    __shared__ __align__(16) u16 As[4096];
    __shared__ __align__(16) u16 Bs[16384];
    int tid = threadIdx.x;
    int w = tid >> 6, lane = tid & 63, quad = lane >> 4, l16 = lane & 15;
    int m0 = blockIdx.x * 64;
    int col0 = blockIdx.y * 256;
    int e = blockIdx.z;
    f32x4 acc[4][4] = {};
    const u16* Ag = A + e * aE + (size_t)m0 * lda;
    const u16* Bg = BT + e * bE + (size_t)col0 * lda;
    int kiters = lda >> 6;
    for (int kit = 0; kit < kiters; ++kit) {
        stageA64(Ag + kit * 64, lda, As, tid);
        stageB64(Bg + kit * 64, lda, Bs, tid);
        __syncthreads();
        compute64(As, Bs, acc, w, l16, quad);
        __syncthreads();
    }
#pragma unroll
    for (int nt = 0; nt < 4; ++nt) {
        int col = col0 + w * 64 + nt * 16 + l16;
        float bvv = bias[e * biasE + col];
#pragma unroll
        for (int mt = 0; mt < 4; ++mt)
#pragma unroll
            for (int r = 0; r < 4; ++r) {
                int row = m0 + mt * 16 + quad * 4 + r;
                outp[e * oE + (size_t)row * ldo + col] = f2bf(gelu_exact(acc[mt][nt][r] + bvv));
            }
    }
}

// ---------------------------------------------------------------------------
// K3: combine — 32-row tiles, loop e: h2@W3 + b3 + x -> LN -> *eg+eb,
// out += w[row][e]*y; lb_loss finalized by block 0.
// ---------------------------------------------------------------------------
__global__ __launch_bounds__(256) void combine_kernel(
    const u16* __restrict__ h2, const u16* __restrict__ W3T,
    const float* __restrict__ b3, const float* __restrict__ eg, const float* __restrict__ eb,
    const u16* __restrict__ xbf, const float* __restrict__ wr,
    const float* __restrict__ lbacc, float* __restrict__ outp) {
    __shared__ __align__(16) u16 As[2048];    // 4KB: 32 rows x 64 k
    __shared__ __align__(16) u16 Bs[16384];   // 32KB
    __shared__ __align__(16) u16 xs[8192];    // 16KB: 32 rows x 256 bf16
    __shared__ float wl[128];
    int tid = threadIdx.x;
    int w = tid >> 6, lane = tid & 63, quad = lane >> 4, l16 = lane & 15;
    int m0 = blockIdx.x * 32;
    if (blockIdx.x == 0 && tid == 0) {        // lb_loss (lbacc complete: fusion done)
        float lb = 0.f;
#pragma unroll
        for (int e = 0; e < 4; ++e)
            lb += (lbacc[4 + e] / 32768.f) * (lbacc[e] / 16384.f);
        outp[4194304] = 4.f * lb;
    }
#pragma unroll
    for (int i = 0; i < 4; ++i) {
        int s = i * 256 + tid;
        *(uint4*)(xs + s * 8) = *(const uint4*)(xbf + (size_t)m0 * 256 + s * 8);
    }
    if (tid < 128) wl[tid] = wr[(size_t)m0 * 4 + tid];
    float2* red = (float2*)As;               // alias (barrier-guarded)
    float* muv = (float*)((char*)As + 1024);
    float* rsv = (float*)((char*)As + 1152);
    f32x4 oacc[2][4] = {};
    for (int e = 0; e < 4; ++e) {
        __syncthreads();                     // covers xs/wl (e=0), red reuse (e>0)
        f32x4 acc[2][4] = {};
        const u16* Ag = h2 + ((size_t)e * 16384 + m0) * 256;
        const u16* Bg = W3T + (size_t)e * 65536;
        for (int kit = 0; kit < 4; ++kit) {
            stageA64_R32(Ag + kit * 64, 256, As, tid);
            stageB64(Bg + kit * 64, 256, Bs, tid);
            __syncthreads();
            compute64_R32(As, Bs, acc, w, l16, quad);
            __syncthreads();
        }
        float b3v[4], egv[4], ebv[4];
#pragma unroll
        for (int nt = 0; nt < 4; ++nt) {
            int col = w * 64 + nt * 16 + l16;
            b3v[nt] = b3[e * 256 + col]; egv[nt] = eg[e * 256 + col]; ebv[nt] = eb[e * 256 + col];
        }
#pragma unroll
        for (int mt = 0; mt < 2; ++mt)
#pragma unroll
            for (int r = 0; r < 4; ++r) {
                int rl = mt * 16 + quad * 4 + r;
                float ss = 0.f, qq = 0.f;
#pragma unroll
                for (int nt = 0; nt < 4; ++nt) {
                    int col = w * 64 + nt * 16 + l16;
                    float v = acc[mt][nt][r] + b3v[nt] + bf2f(xs[rl * 256 + col]);
                    acc[mt][nt][r] = v;
                    ss += v; qq += v * v;
                }
#pragma unroll
                for (int d = 1; d < 16; d <<= 1) { ss += __shfl_xor(ss, d); qq += __shfl_xor(qq, d); }
                if (l16 == 0) red[w * 32 + rl] = make_float2(ss, qq);
            }
        __syncthreads();
        if (tid < 32) {
            float ss = 0.f, qq = 0.f;
#pragma unroll
            for (int ww = 0; ww < 4; ++ww) { float2 t = red[ww * 32 + tid]; ss += t.x; qq += t.y; }
            float mu = ss * (1.f / 256.f);
            float var = qq * (1.f / 256.f) - mu * mu;
            muv[tid] = mu;
            rsv[tid] = 1.f / sqrtf(var + 1e-5f);
        }
        __syncthreads();
#pragma unroll
        for (int mt = 0; mt < 2; ++mt)
#pragma unroll
            for (int r = 0; r < 4; ++r) {
                int rl = mt * 16 + quad * 4 + r;
                float mu = muv[rl], rs = rsv[rl], we = wl[rl * 4 + e];
#pragma unroll
                for (int nt = 0; nt < 4; ++nt) {
                    float y = (acc[mt][nt][r] - mu) * rs * egv[nt] + ebv[nt];
                    oacc[mt][nt][r] += we * y;
                }
            }
    }
#pragma unroll
    for (int mt = 0; mt < 2; ++mt)
#pragma unroll
        for (int r = 0; r < 4; ++r) {
            int rl = mt * 16 + quad * 4 + r;
#pragma unroll
            for (int nt = 0; nt < 4; ++nt) {
                int col = w * 64 + nt * 16 + l16;
                outp[(size_t)(m0 + rl) * 256 + col] = oacc[mt][nt][r];
            }
        }
}

// ---------------------------------------------------------------------------
extern "C" void kernel_launch(void* const* d_in, const int* in_sizes, int n_in,
                              void* d_out, int out_size, void* d_ws, size_t ws_size,
                              hipStream_t stream) {
    const float* vis   = (const float*)d_in[0];
    const float* lang  = (const float*)d_in[1];
    const float* state = (const float*)d_in[2];
    const float* Wf    = (const float*)d_in[3];
    const float* bf_   = (const float*)d_in[4];
    const float* gf    = (const float*)d_in[5];
    const float* bfln  = (const float*)d_in[6];
    const float* Wg    = (const float*)d_in[7];
    const float* W1    = (const float*)d_in[8];
    const float* b1    = (const float*)d_in[9];
    const float* W2    = (const float*)d_in[10];
    const float* b2    = (const float*)d_in[11];
    const float* W3    = (const float*)d_in[12];
    const float* b3    = (const float*)d_in[13];
    const float* eg    = (const float*)d_in[14];
    const float* eb    = (const float*)d_in[15];
    float* outp = (float*)d_out;

    char* ws = (char*)d_ws;
    size_t off = 0;
    float* lbacc = (float*)(ws + off); off += 256;
    u16* WFT  = (u16*)(ws + off); off += 819200UL;     // WfT [256][1600]
    u16* W1T  = (u16*)(ws + off); off += 1048576UL;    // [E][512][256]
    u16* W2T  = (u16*)(ws + off); off += 1048576UL;    // [E][256][512]
    u16* W3T  = (u16*)(ws + off); off += 524288UL;     // [E][256][256]
    u16* XBF  = (u16*)(ws + off); off += 8388608UL;    // x bf16 [B][256]
    float* WR = (float*)(ws + off); off += 262144UL;   // gate weights [B][4]
    u16* H1   = (u16*)(ws + off); off += 67108864UL;   // [E][B][512]
    u16* H2   = (u16*)(ws + off); off += 33554432UL;   // [E][B][256]
    if (ws_size < off) return;

    int prep_blocks = (PREP_ITEMS + 255) / 256;
    prep_kernel<<<prep_blocks, 256, 0, stream>>>(Wf, W1, W2, W3, WFT, W1T, W2T, W3T, lbacc);
    fusion_kernel<<<512, 256, 0, stream>>>(vis, lang, state, WFT, bf_, gf, bfln, Wg,
                                           XBF, WR, lbacc);
    expert_gemm_kernel<<<dim3(256, 2, 4), 256, 0, stream>>>(
        XBF, 256, 0, W1T, 131072, b1, 512, H1, 512, 8388608UL);
    expert_gemm_kernel<<<dim3(256, 1, 4), 256, 0, stream>>>(
        H1, 512, 8388608UL, W2T, 131072, b2, 256, H2, 256, 4194304UL);
    combine_kernel<<<512, 256, 0, stream>>>(H2, W3T, b3, eg, eb, XBF, WR, lbacc, outp);
}